// Round 5
// baseline (180.511 us; speedup 1.0000x reference)
//
#include <hip/hip_runtime.h>
#include <hip/hip_bf16.h>
#include <math.h>

// DotProductAttention: S=2048, B=2, NH=16, HD=128, fp32 in/out, mask=all-ones.
// R5: R4 swapped-operand 32x32 structure, re-gridded for occupancy:
//   - BQ=128, 4 waves/block, 512 blocks -> 2 independent blocks/CU
//     (decoupled barriers; m114 MFMA/VALU cross-block co-schedule)
//   - XCD-aware block swizzle: each XCD owns 4 heads (K/V panels L2-resident)
//   - v_cvt_pk_bf16_f32 for P-pack (T12), tree reductions, setprio (T5)

#define SQ 2048
#define NBH 32
#define HD 128
#define RSTRIDE 4096          // B*NH*HD
#define BQ 128                // q-rows per block (4 waves x 32)
#define BK 64                 // kv tile
#define NKT (SQ / BK)
#define HELEMS (SQ * HD)      // per-head elems per tensor
#define SCALE_LOG2E 0.12751879523499918f  // log2(e)/sqrt(128)
#define THR_LOG2 8.0f

typedef __attribute__((ext_vector_type(4)))  float f32x4;
typedef __attribute__((ext_vector_type(16))) float f32x16;
typedef __attribute__((ext_vector_type(4)))  short s16x4;
typedef __attribute__((ext_vector_type(8)))  short s16x8;

#define MFMA32(a, b, c) __builtin_amdgcn_mfma_f32_32x32x16_bf16((a), (b), (c), 0, 0, 0)

__device__ __forceinline__ short f2bf(float f) {
    __hip_bfloat16 h = __float2bfloat16(f);
    return __builtin_bit_cast(short, h);
}
__device__ __forceinline__ unsigned pk2(float lo, float hi) {
    unsigned r;
    asm("v_cvt_pk_bf16_f32 %0, %1, %2" : "=v"(r) : "v"(lo), "v"(hi));
    return r;
}

__device__ __forceinline__ void stage16(const void* g, void* l) {
    __builtin_amdgcn_global_load_lds(
        (const __attribute__((address_space(1))) unsigned int*)g,
        (__attribute__((address_space(3))) unsigned int*)l, 16, 0, 0);
}

// ---------------------------------------------------------------------------
// Pre-pass 1: Q,K fp32 [s][bh][hd] -> bf16 [bh][s][hd] in ws.
// Q scaled by SCALE_LOG2E (plain layout). K: 16B chunks pre-swizzled
// (c ^= s&7) so linear global_load_lds yields the swizzled LDS image.
__global__ __launch_bounds__(256) void prep_qk(const float* __restrict__ Q,
                                               const float* __restrict__ K,
                                               short* __restrict__ wq,
                                               short* __restrict__ wk) {
    const int id = blockIdx.x * 256 + threadIdx.x;   // 1M chunk ids
    const int bh = id >> 15;
    const int s  = (id >> 4) & 2047;
    const int c  = id & 15;
    const size_t outoff = (size_t)bh * HELEMS + (size_t)s * HD + c * 8;
    {   // Q (plain)
        const float* src = Q + (size_t)s * RSTRIDE + bh * HD + c * 8;
        f32x4 a = *(const f32x4*)src;
        f32x4 b = *(const f32x4*)(src + 4);
        s16x8 f;
        #pragma unroll
        for (int j = 0; j < 4; ++j) {
            f[j]     = f2bf(a[j] * SCALE_LOG2E);
            f[4 + j] = f2bf(b[j] * SCALE_LOG2E);
        }
        *(s16x8*)(wq + outoff) = f;
    }
    {   // K (chunk-swizzled)
        const int cl = c ^ (s & 7);
        const float* src = K + (size_t)s * RSTRIDE + bh * HD + cl * 8;
        f32x4 a = *(const f32x4*)src;
        f32x4 b = *(const f32x4*)(src + 4);
        s16x8 f;
        #pragma unroll
        for (int j = 0; j < 4; ++j) { f[j] = f2bf(a[j]); f[4 + j] = f2bf(b[j]); }
        *(s16x8*)(wk + outoff) = f;
    }
}

// ---------------------------------------------------------------------------
// Pre-pass 2: V fp32 [s][bh][hd] -> bf16 transposed [bh][dim][s] in ws,
// 8-key chunks pre-swizzled per 64-key block: ws[bh][dim][kt*64 + c*8 + j] =
//   V[kt*64 + (c^(dim&7))*8 + j][bh][dim].
__global__ __launch_bounds__(256) void prep_v(const float* __restrict__ V,
                                              short* __restrict__ wv) {
    const int kt = blockIdx.x;   // 32
    const int bh = blockIdx.y;   // 32
    const int tid = threadIdx.x;
    __shared__ short L[64 * 132];  // [key_local][dim], pitch 132 (128+4 pad)

    #pragma unroll
    for (int it = 0; it < 8; ++it) {
        const int id = it * 256 + tid;       // 0..2047
        const int row = id >> 5, p = id & 31;
        f32x4 a = *(const f32x4*)(V + (size_t)(kt * BK + row) * RSTRIDE + bh * HD + p * 4);
        s16x4 f;
        #pragma unroll
        for (int j = 0; j < 4; ++j) f[j] = f2bf(a[j]);
        *(s16x4*)&L[row * 132 + p * 4] = f;
    }
    __syncthreads();
    #pragma unroll
    for (int it = 0; it < 4; ++it) {
        const int id = it * 256 + tid;       // 0..1023
        const int dim = id >> 3, c = id & 7;
        const int klb = (c ^ (dim & 7)) * 8;
        s16x8 f;
        #pragma unroll
        for (int j = 0; j < 8; ++j) f[j] = L[(klb + j) * 132 + dim];
        *(s16x8*)(wv + (size_t)bh * HELEMS + (size_t)dim * SQ + kt * BK + c * 8) = f;
    }
}

// ---------------------------------------------------------------------------
// Main flash kernel: 4 waves x 32 q-rows (BQ=128); KVBLK=64; swapped-operand
// 32x32x16 MFMA. Grid = 512 linear blocks, XCD-swizzled (8 XCDs x 4 heads).
__global__ __launch_bounds__(256) void fa_fwd3(const short* __restrict__ Qb,
                                               const short* __restrict__ Kb,
                                               const short* __restrict__ Vb,
                                               float* __restrict__ O) {
    // XCD-aware decode: round-robin dispatch (id % 8 = XCD) -> XCD x owns
    // heads 4x..4x+3, all 16 q-tiles of each.
    const int id  = blockIdx.x;
    const int xcd = id & 7;
    const int s8  = id >> 3;          // 0..63
    const int bh  = xcd * 4 + (s8 >> 4);
    const int qt  = s8 & 15;

    const int tid  = threadIdx.x;
    const int w    = tid >> 6;     // wave 0..3
    const int lane = tid & 63;
    const int l32  = lane & 31;
    const int hi   = lane >> 5;

    __shared__ short Kt[2][BK * HD];   // [key][dim] swizzled image, 2x16KB
    __shared__ short Vt[2][HD * BK];   // [dim][key] swizzled image, 2x16KB

    const size_t hb = (size_t)bh * HELEMS;
    const int q = qt * BQ + w * 32 + l32;   // this lane's q-row

    // Q fragments: qf[kd][i] = Q[q][16*kd + 8*hi + i], scale pre-folded
    s16x8 qf[8];
    {
        const short* qp = Qb + hb + (size_t)q * HD + hi * 8;
        #pragma unroll
        for (int kd = 0; kd < 8; ++kd) qf[kd] = *(const s16x8*)(qp + kd * 16);
    }

    // acc[db][reg] = O[q][32*db + (reg&3) + 8*(reg>>2) + 4*hi]  (O^T orient.)
    f32x16 acc[4];
    #pragma unroll
    for (int db = 0; db < 4; ++db)
        #pragma unroll
        for (int i = 0; i < 16; ++i) acc[db][i] = 0.0f;
    float m = -INFINITY, l = 0.0f;

    // staging: 8 x global_load_lds(16B) per wave per tile (K 16KB + V 16KB)
    auto STAGE = [&](int kt, int buf) {
        // K: wave w stages keys [w*16 .. w*16+15] (linear, ws pre-swizzled)
        const short* kg = Kb + hb + (size_t)kt * (BK * HD) + w * 2048 + lane * 8;
        short* kld = &Kt[buf][w * 2048 + lane * 8];
        #pragma unroll
        for (int j = 0; j < 4; ++j)
            stage16(kg + j * 512, kld + j * 512);
        // V: wave w stages dims [w*32 .. w*32+31]
        #pragma unroll
        for (int j = 0; j < 4; ++j) {
            const int dim = w * 32 + j * 8 + (lane >> 3);
            const short* vg = Vb + hb + (size_t)dim * SQ + kt * BK + (lane & 7) * 8;
            stage16(vg, &Vt[buf][(w * 32 + j * 8) * BK + lane * 8]);
        }
    };

    STAGE(0, 0);
    __syncthreads();
    int buf = 0;

    for (int kt = 0; kt < NKT; ++kt) {
        if (kt + 1 < NKT) STAGE(kt + 1, buf ^ 1);

        // ---- QK^T (swapped): sc[kb] = S^T, lane holds 16 keys for row q ----
        // key = 32*kb + (reg&3) + 8*(reg>>2) + 4*hi
        f32x16 sc[2];
        __builtin_amdgcn_s_setprio(1);
        #pragma unroll
        for (int kb = 0; kb < 2; ++kb) {
            #pragma unroll
            for (int i = 0; i < 16; ++i) sc[kb][i] = 0.0f;
            const int key = kb * 32 + l32;
            #pragma unroll
            for (int kd = 0; kd < 8; ++kd) {
                const int elem = key * HD + (((kd << 1) | hi) ^ (key & 7)) * 8;
                s16x8 kf = *(const s16x8*)&Kt[buf][elem];
                sc[kb] = MFMA32(kf, qf[kd], sc[kb]);
            }
        }
        __builtin_amdgcn_s_setprio(0);

        // ---- online softmax, in-register (log2 domain, defer-max) ----
        // tree-structured max: 4 parallel chains
        float mt0 = sc[0][0], mt1 = sc[0][1], mt2 = sc[0][2], mt3 = sc[0][3];
        #pragma unroll
        for (int kb = 0; kb < 2; ++kb)
            #pragma unroll
            for (int r = 0; r < 16; r += 4) {
                if (kb == 0 && r == 0) continue;
                mt0 = fmaxf(mt0, sc[kb][r + 0]);
                mt1 = fmaxf(mt1, sc[kb][r + 1]);
                mt2 = fmaxf(mt2, sc[kb][r + 2]);
                mt3 = fmaxf(mt3, sc[kb][r + 3]);
            }
        const float mt = fmaxf(fmaxf(mt0, mt1), fmaxf(mt2, mt3));
        const float m0 = fmaxf(mt, __shfl_xor(mt, 32, 64));
        const bool need = (m0 > m + THR_LOG2);
        const float mn = need ? fmaxf(m, m0) : m;
        if (__any(need)) {
            const float alpha = exp2f(m - mn);
            m = mn;
            l *= alpha;
            #pragma unroll
            for (int db = 0; db < 4; ++db) acc[db] *= alpha;
        }
        // exp + tree-structured sum: 4 partials
        float lsp0 = 0.f, lsp1 = 0.f, lsp2 = 0.f, lsp3 = 0.f;
        #pragma unroll
        for (int kb = 0; kb < 2; ++kb)
            #pragma unroll
            for (int r = 0; r < 16; r += 4) {
                float p0 = exp2f(sc[kb][r + 0] - m);
                float p1 = exp2f(sc[kb][r + 1] - m);
                float p2 = exp2f(sc[kb][r + 2] - m);
                float p3 = exp2f(sc[kb][r + 3] - m);
                sc[kb][r + 0] = p0; sc[kb][r + 1] = p1;
                sc[kb][r + 2] = p2; sc[kb][r + 3] = p3;
                lsp0 += p0; lsp1 += p1; lsp2 += p2; lsp3 += p3;
            }
        l += (lsp0 + lsp1) + (lsp2 + lsp3);

        // ---- P -> B-frag via v_cvt_pk_bf16_f32 + permlane32_swap (T12) ----
        // pa[ks] holds keys 16*ks + 8*hi + {0..7} of row q
        s16x8 pa[4];
        #pragma unroll
        for (int ks = 0; ks < 4; ++ks) {
            const int kb = ks >> 1;
            const int j  = (2 * ks) & 3, j2 = (2 * ks + 1) & 3;
            unsigned a0 = pk2(sc[kb][4 * j + 0],  sc[kb][4 * j + 1]);
            unsigned a1 = pk2(sc[kb][4 * j + 2],  sc[kb][4 * j + 3]);
            unsigned b0 = pk2(sc[kb][4 * j2 + 0], sc[kb][4 * j2 + 1]);
            unsigned b1 = pk2(sc[kb][4 * j2 + 2], sc[kb][4 * j2 + 3]);
#if __has_builtin(__builtin_amdgcn_permlane32_swap)
            auto r0 = __builtin_amdgcn_permlane32_swap(a0, b0, false, false);
            auto r1 = __builtin_amdgcn_permlane32_swap(a1, b1, false, false);
            union { unsigned u[4]; s16x8 v; } P;
            P.u[0] = r0[0]; P.u[1] = r1[0]; P.u[2] = r0[1]; P.u[3] = r1[1];
#else
            const unsigned s0 = __shfl_xor(hi ? a0 : b0, 32, 64);
            const unsigned s1 = __shfl_xor(hi ? a1 : b1, 32, 64);
            union { unsigned u[4]; s16x8 v; } P;
            P.u[0] = hi ? s0 : a0; P.u[1] = hi ? s1 : a1;
            P.u[2] = hi ? b0 : s0; P.u[3] = hi ? b1 : s1;
#endif
            pa[ks] = P.v;
        }

        // ---- PV (swapped): acc[db] += V^T(32d x 16k) * P^T(16k x 32q) ----
        __builtin_amdgcn_s_setprio(1);
        #pragma unroll
        for (int db = 0; db < 4; ++db) {
            const int dim = db * 32 + l32;
            #pragma unroll
            for (int ks = 0; ks < 4; ++ks) {
                const int elem = dim * BK + ((((ks << 1) | hi) ^ (dim & 7)) << 3);
                s16x8 vf = *(const s16x8*)&Vt[buf][elem];
                acc[db] = MFMA32(vf, pa[ks], acc[db]);
            }
        }
        __builtin_amdgcn_s_setprio(0);

        __syncthreads();   // drains vmcnt(0): next tile staged; cur reads done
        buf ^= 1;
    }

    // ---- epilogue: combine halves' l, normalize, store O fp32 ----
    const float lf = l + __shfl_xor(l, 32, 64);
    const float invl = 1.0f / lf;
    float* op = O + (size_t)q * RSTRIDE + bh * HD;
    #pragma unroll
    for (int db = 0; db < 4; ++db)
        #pragma unroll
        for (int j = 0; j < 4; ++j) {
            f32x4 o;
            #pragma unroll
            for (int r = 0; r < 4; ++r) o[r] = acc[db][4 * j + r] * invl;
            *(f32x4*)(op + db * 32 + j * 8 + hi * 4) = o;
        }
}

// ---------------------------------------------------------------------------
// Legacy fallback (R1 kernel) if ws_size is insufficient.
__global__ __launch_bounds__(256) void fa_fwd_legacy(const float* __restrict__ Q,
                                                     const float* __restrict__ K,
                                                     const float* __restrict__ V,
                                                     float* __restrict__ O) {
    const int qt   = blockIdx.x;
    const int bh   = blockIdx.y;
    const int tid  = threadIdx.x;
    const int w    = tid >> 6;
    const int lane = tid & 63;
    const int l16  = lane & 15;
    const int lg   = lane >> 4;

    __shared__ short Kt[BK * HD];
    __shared__ short Vt[HD * BK];
    __shared__ short Pl[4][16 * 72];

    const int headoff = bh * HD;
    s16x8 qf[4];
    {
        const int qrow = qt * 64 + w * 16 + l16;
        const float* qp = Q + (size_t)qrow * RSTRIDE + headoff + lg * 8;
        #pragma unroll
        for (int ks = 0; ks < 4; ++ks) {
            f32x4 a = *(const f32x4*)(qp + ks * 32);
            f32x4 b = *(const f32x4*)(qp + ks * 32 + 4);
            s16x8 f;
            #pragma unroll
            for (int j = 0; j < 4; ++j) {
                f[j]     = f2bf(a[j] * SCALE_LOG2E);
                f[4 + j] = f2bf(b[j] * SCALE_LOG2E);
            }
            qf[ks] = f;
        }
    }
    f32x4 acc[8];
    #pragma unroll
    for (int i = 0; i < 8; ++i)
        #pragma unroll
        for (int j = 0; j < 4; ++j) acc[i][j] = 0.0f;
    float mrow[4], lrow[4];
    #pragma unroll
    for (int r = 0; r < 4; ++r) { mrow[r] = -INFINITY; lrow[r] = 0.0f; }
    const int skey = tid >> 2;
    const int sdc  = tid & 3;
    const int va   = tid >> 3;
    const int vdc  = tid & 7;

    for (int kt = 0; kt < NKT; ++kt) {
        __syncthreads();
        {
            const float* kp = K + (size_t)(kt * BK + skey) * RSTRIDE + headoff;
            #pragma unroll
            for (int c = 0; c < 4; ++c) {
                const int d0 = c * 32 + sdc * 8;
                f32x4 a = *(const f32x4*)(kp + d0);
                f32x4 b = *(const f32x4*)(kp + d0 + 4);
                s16x8 f;
                #pragma unroll
                for (int j = 0; j < 4; ++j) { f[j] = f2bf(a[j]); f[4 + j] = f2bf(b[j]); }
                const int elem = (skey * HD + d0) ^ ((skey & 7) << 3);
                *(s16x8*)&Kt[elem] = f;
            }
        }
        {
            const float* vp0 = V + (size_t)(kt * BK + va * 2) * RSTRIDE + headoff;
            const float* vp1 = vp0 + RSTRIDE;
            #pragma unroll
            for (int c = 0; c < 4; ++c) {
                const int d0 = c * 32 + vdc * 4;
                f32x4 a0 = *(const f32x4*)(vp0 + d0);
                f32x4 a1 = *(const f32x4*)(vp1 + d0);
                #pragma unroll
                for (int j = 0; j < 4; ++j) {
                    const int dim = d0 + j;
                    const int s = (dim ^ (dim >> 3)) & 7;
                    const int elem = (dim * BK + va * 2) ^ (s << 3);
                    union { short u[2]; int i; } pr;
                    pr.u[0] = f2bf(a0[j]);
                    pr.u[1] = f2bf(a1[j]);
                    *(int*)&Vt[elem] = pr.i;
                }
            }
        }
        __syncthreads();
        f32x4 sc[4];
        #pragma unroll
        for (int t = 0; t < 4; ++t) {
            #pragma unroll
            for (int j = 0; j < 4; ++j) sc[t][j] = 0.0f;
            const int key = t * 16 + l16;
            #pragma unroll
            for (int ks = 0; ks < 4; ++ks) {
                const int elem = (key * HD + ks * 32 + lg * 8) ^ ((key & 7) << 3);
                s16x8 kf = *(const s16x8*)&Kt[elem];
                sc[t] = __builtin_amdgcn_mfma_f32_16x16x32_bf16(qf[ks], kf, sc[t], 0, 0, 0);
            }
        }
        float alpha[4];
        #pragma unroll
        for (int r = 0; r < 4; ++r) {
            float m0 = fmaxf(fmaxf(sc[0][r], sc[1][r]), fmaxf(sc[2][r], sc[3][r]));
            #pragma unroll
            for (int d = 1; d < 16; d <<= 1) m0 = fmaxf(m0, __shfl_xor(m0, d, 64));
            const float mnew = fmaxf(mrow[r], m0);
            alpha[r] = exp2f(mrow[r] - mnew);
            mrow[r] = mnew;
        }
        float rsum[4] = {0.f, 0.f, 0.f, 0.f};
        #pragma unroll
        for (int t = 0; t < 4; ++t)
            #pragma unroll
            for (int r = 0; r < 4; ++r) {
                const float p = exp2f(sc[t][r] - mrow[r]);
                sc[t][r] = p;
                rsum[r] += p;
            }
        #pragma unroll
        for (int r = 0; r < 4; ++r) {
            #pragma unroll
            for (int d = 1; d < 16; d <<= 1) rsum[r] += __shfl_xor(rsum[r], d, 64);
            lrow[r] = lrow[r] * alpha[r] + rsum[r];
        }
        #pragma unroll
        for (int ct = 0; ct < 8; ++ct)
            #pragma unroll
            for (int r = 0; r < 4; ++r) acc[ct][r] *= alpha[r];
        #pragma unroll
        for (int t = 0; t < 4; ++t)
            #pragma unroll
            for (int r = 0; r < 4; ++r)
                Pl[w][(lg * 4 + r) * 72 + t * 16 + l16] = f2bf(sc[t][r]);
        s16x8 pf[2];
        #pragma unroll
        for (int ks = 0; ks < 2; ++ks)
            pf[ks] = *(const s16x8*)&Pl[w][l16 * 72 + ks * 32 + lg * 8];
        #pragma unroll
        for (int ct = 0; ct < 8; ++ct) {
            const int dim = ct * 16 + l16;
            const int s = (dim ^ (dim >> 3)) & 7;
            #pragma unroll
            for (int ks = 0; ks < 2; ++ks) {
                const int elem = (dim * BK + ks * 32 + lg * 8) ^ (s << 3);
                s16x8 vf = *(const s16x8*)&Vt[elem];
                acc[ct] = __builtin_amdgcn_mfma_f32_16x16x32_bf16(pf[ks], vf, acc[ct], 0, 0, 0);
            }
        }
    }
    float inv_l[4];
    #pragma unroll
    for (int r = 0; r < 4; ++r) inv_l[r] = 1.0f / lrow[r];
    const int orow0 = qt * 64 + w * 16;
    #pragma unroll
    for (int ct = 0; ct < 8; ++ct) {
        const int col = ct * 16 + l16;
        #pragma unroll
        for (int r = 0; r < 4; ++r) {
            const int row = orow0 + lg * 4 + r;
            O[(size_t)row * RSTRIDE + headoff + col] = acc[ct][r] * inv_l[r];
        }
    }
}

extern "C" void kernel_launch(void* const* d_in, const int* in_sizes, int n_in,
                              void* d_out, int out_size, void* d_ws, size_t ws_size,
                              hipStream_t stream) {
    const float* Q = (const float*)d_in[0];
    const float* K = (const float*)d_in[1];
    const float* V = (const float*)d_in[2];
    float* O = (float*)d_out;

    const size_t need = (size_t)3 * NBH * HELEMS * sizeof(short);  // 50.3 MB
    if (ws_size >= need) {
        short* wq = (short*)d_ws;
        short* wk = wq + (size_t)NBH * HELEMS;
        short* wv = wk + (size_t)NBH * HELEMS;
        prep_qk<<<4096, 256, 0, stream>>>(Q, K, wq, wk);
        prep_v<<<dim3(NKT, NBH), 256, 0, stream>>>(V, wv);
        fa_fwd3<<<(SQ / BQ) * NBH, 256, 0, stream>>>(wq, wk, wv, O);
    } else {
        fa_fwd_legacy<<<dim3(SQ / 64, NBH), 256, 0, stream>>>(Q, K, V, O);
    }
}

// Round 6
// 133.173 us; speedup vs baseline: 1.3555x; 1.3555x over previous
//
#include <hip/hip_runtime.h>
#include <hip/hip_bf16.h>
#include <math.h>

// DotProductAttention: S=2048, B=2, NH=16, HD=128, fp32 in/out, mask=all-ones.
// R6: R4 8-wave swapped-operand 32x32 structure (best measured: 117us) plus:
//   - XCD-aware block swizzle (kept from R5: FETCH 139->25 GB)
//   - triple-buffered LDS (96KB), depth-2 prefetch, counted vmcnt(4) at the
//     barrier (T4): loads stay in flight across barriers, no vmcnt(0) drain
//   - v_cvt_pk_bf16_f32 P-pack, tree reductions, setprio (kept from R5)

#define SQ 2048
#define NBH 32
#define HD 128
#define RSTRIDE 4096          // B*NH*HD
#define BQ 256                // q-rows per block (8 waves x 32)
#define BK 64                 // kv tile
#define NKT (SQ / BK)
#define HELEMS (SQ * HD)      // per-head elems per tensor
#define SCALE_LOG2E 0.12751879523499918f  // log2(e)/sqrt(128)
#define THR_LOG2 8.0f

typedef __attribute__((ext_vector_type(4)))  float f32x4;
typedef __attribute__((ext_vector_type(16))) float f32x16;
typedef __attribute__((ext_vector_type(4)))  short s16x4;
typedef __attribute__((ext_vector_type(8)))  short s16x8;

#define MFMA32(a, b, c) __builtin_amdgcn_mfma_f32_32x32x16_bf16((a), (b), (c), 0, 0, 0)
#define WAITV(N) asm volatile("s_waitcnt vmcnt(" #N ")" ::: "memory")

__device__ __forceinline__ short f2bf(float f) {
    __hip_bfloat16 h = __float2bfloat16(f);
    return __builtin_bit_cast(short, h);
}
__device__ __forceinline__ unsigned pk2(float lo, float hi) {
    unsigned r;
    asm("v_cvt_pk_bf16_f32 %0, %1, %2" : "=v"(r) : "v"(lo), "v"(hi));
    return r;
}

__device__ __forceinline__ void stage16(const void* g, void* l) {
    __builtin_amdgcn_global_load_lds(
        (const __attribute__((address_space(1))) unsigned int*)g,
        (__attribute__((address_space(3))) unsigned int*)l, 16, 0, 0);
}

// ---------------------------------------------------------------------------
// Pre-pass 1: Q,K fp32 [s][bh][hd] -> bf16 [bh][s][hd] in ws.
// Q scaled by SCALE_LOG2E (plain layout). K: 16B chunks pre-swizzled
// (c ^= s&7) so linear global_load_lds yields the swizzled LDS image.
__global__ __launch_bounds__(256) void prep_qk(const float* __restrict__ Q,
                                               const float* __restrict__ K,
                                               short* __restrict__ wq,
                                               short* __restrict__ wk) {
    const int id = blockIdx.x * 256 + threadIdx.x;   // 1M chunk ids
    const int bh = id >> 15;
    const int s  = (id >> 4) & 2047;
    const int c  = id & 15;
    const size_t outoff = (size_t)bh * HELEMS + (size_t)s * HD + c * 8;
    {   // Q (plain)
        const float* src = Q + (size_t)s * RSTRIDE + bh * HD + c * 8;
        f32x4 a = *(const f32x4*)src;
        f32x4 b = *(const f32x4*)(src + 4);
        s16x8 f;
        #pragma unroll
        for (int j = 0; j < 4; ++j) {
            f[j]     = f2bf(a[j] * SCALE_LOG2E);
            f[4 + j] = f2bf(b[j] * SCALE_LOG2E);
        }
        *(s16x8*)(wq + outoff) = f;
    }
    {   // K (chunk-swizzled)
        const int cl = c ^ (s & 7);
        const float* src = K + (size_t)s * RSTRIDE + bh * HD + cl * 8;
        f32x4 a = *(const f32x4*)src;
        f32x4 b = *(const f32x4*)(src + 4);
        s16x8 f;
        #pragma unroll
        for (int j = 0; j < 4; ++j) { f[j] = f2bf(a[j]); f[4 + j] = f2bf(b[j]); }
        *(s16x8*)(wk + outoff) = f;
    }
}

// ---------------------------------------------------------------------------
// Pre-pass 2: V fp32 [s][bh][hd] -> bf16 transposed [bh][dim][s] in ws,
// 8-key chunks pre-swizzled per 64-key block: ws[bh][dim][kt*64 + c*8 + j] =
//   V[kt*64 + (c^(dim&7))*8 + j][bh][dim].
__global__ __launch_bounds__(256) void prep_v(const float* __restrict__ V,
                                              short* __restrict__ wv) {
    const int kt = blockIdx.x;   // 32
    const int bh = blockIdx.y;   // 32
    const int tid = threadIdx.x;
    __shared__ short L[64 * 132];  // [key_local][dim], pitch 132 (128+4 pad)

    #pragma unroll
    for (int it = 0; it < 8; ++it) {
        const int id = it * 256 + tid;       // 0..2047
        const int row = id >> 5, p = id & 31;
        f32x4 a = *(const f32x4*)(V + (size_t)(kt * BK + row) * RSTRIDE + bh * HD + p * 4);
        s16x4 f;
        #pragma unroll
        for (int j = 0; j < 4; ++j) f[j] = f2bf(a[j]);
        *(s16x4*)&L[row * 132 + p * 4] = f;
    }
    __syncthreads();
    #pragma unroll
    for (int it = 0; it < 4; ++it) {
        const int id = it * 256 + tid;       // 0..1023
        const int dim = id >> 3, c = id & 7;
        const int klb = (c ^ (dim & 7)) * 8;
        s16x8 f;
        #pragma unroll
        for (int j = 0; j < 8; ++j) f[j] = L[(klb + j) * 132 + dim];
        *(s16x8*)(wv + (size_t)bh * HELEMS + (size_t)dim * SQ + kt * BK + c * 8) = f;
    }
}

// ---------------------------------------------------------------------------
// Main flash kernel: 8 waves x 32 q-rows (BQ=256); KVBLK=64; swapped-operand
// 32x32x16 MFMA. Grid = 256 linear blocks, XCD-swizzled (8 XCDs x 4 heads).
// Triple-buffered LDS + counted vmcnt(4): no full drain at barriers.
__global__ __launch_bounds__(512) void fa_fwd3(const short* __restrict__ Qb,
                                               const short* __restrict__ Kb,
                                               const short* __restrict__ Vb,
                                               float* __restrict__ O) {
    // XCD-aware decode: dispatch round-robins id%8 across XCDs -> XCD x owns
    // heads 4x..4x+3 (K/V panels: 4 MB = one XCD L2).
    const int id  = blockIdx.x;
    const int xcd = id & 7;
    const int s8  = id >> 3;          // 0..31
    const int bh  = xcd * 4 + (s8 >> 3);
    const int qt  = s8 & 7;

    const int tid  = threadIdx.x;
    const int w    = tid >> 6;     // wave 0..7
    const int lane = tid & 63;
    const int l32  = lane & 31;
    const int hi   = lane >> 5;

    __shared__ short Kt[3][BK * HD];   // [key][dim] swizzled image, 3x16KB
    __shared__ short Vt[3][HD * BK];   // [dim][key] swizzled image, 3x16KB

    const size_t hb = (size_t)bh * HELEMS;
    const int q = qt * BQ + w * 32 + l32;   // this lane's q-row

    // Q fragments: qf[kd][i] = Q[q][16*kd + 8*hi + i], scale pre-folded
    s16x8 qf[8];
    {
        const short* qp = Qb + hb + (size_t)q * HD + hi * 8;
        #pragma unroll
        for (int kd = 0; kd < 8; ++kd) qf[kd] = *(const s16x8*)(qp + kd * 16);
    }

    // acc[db][reg] = O[q][32*db + (reg&3) + 8*(reg>>2) + 4*hi]  (O^T orient.)
    f32x16 acc[4];
    #pragma unroll
    for (int db = 0; db < 4; ++db)
        #pragma unroll
        for (int i = 0; i < 16; ++i) acc[db][i] = 0.0f;
    float m = -INFINITY, l = 0.0f;

    // staging roles (as R4): waves 0-3 stage K, waves 4-7 stage V.
    // 4 x global_load_lds(16B) per wave per tile.
    auto STAGE = [&](int kt, int buf) {
        if (w < 4) {
            const short* kg = Kb + hb + (size_t)kt * (BK * HD) + w * 2048 + lane * 8;
            short* ld = &Kt[buf][w * 2048 + lane * 8];
            #pragma unroll
            for (int j = 0; j < 4; ++j)
                stage16(kg + j * 512, ld + j * 512);
        } else {
            const int w4 = w - 4;
            #pragma unroll
            for (int j = 0; j < 4; ++j) {
                const int dim = w4 * 32 + j * 8 + (lane >> 3);
                const short* vg = Vb + hb + (size_t)dim * SQ + kt * BK + (lane & 7) * 8;
                stage16(vg, &Vt[buf][(w4 * 32 + j * 8) * BK + lane * 8]);
            }
        }
    };

    // Prologue: prefetch tiles 0 and 1.
    STAGE(0, 0);
    STAGE(1, 1);
    int bc = 0;   // compute buffer = kt % 3

    for (int kt = 0; kt < NKT; ++kt) {
        // Own tile-kt loads complete; tile-(kt+1) loads may stay in flight.
        if (kt + 1 < NKT) { WAITV(4); } else { WAITV(0); }
        __builtin_amdgcn_s_barrier();   // all waves' tile-kt loads landed;
                                        // buffer (kt+2)%3 free (read at kt-1)
        if (kt + 2 < NKT) {
            const int bs = bc + 2 >= 3 ? bc - 1 : bc + 2;
            STAGE(kt + 2, bs);
        }

        // ---- QK^T (swapped): sc[kb] = S^T, lane holds 16 keys for row q ----
        // key = 32*kb + (reg&3) + 8*(reg>>2) + 4*hi
        f32x16 sc[2];
        __builtin_amdgcn_s_setprio(1);
        #pragma unroll
        for (int kb = 0; kb < 2; ++kb) {
            #pragma unroll
            for (int i = 0; i < 16; ++i) sc[kb][i] = 0.0f;
            const int key = kb * 32 + l32;
            #pragma unroll
            for (int kd = 0; kd < 8; ++kd) {
                const int elem = key * HD + (((kd << 1) | hi) ^ (key & 7)) * 8;
                s16x8 kf = *(const s16x8*)&Kt[bc][elem];
                sc[kb] = MFMA32(kf, qf[kd], sc[kb]);
            }
        }
        __builtin_amdgcn_s_setprio(0);

        // ---- online softmax, in-register (log2 domain, defer-max) ----
        float mt0 = sc[0][0], mt1 = sc[0][1], mt2 = sc[0][2], mt3 = sc[0][3];
        #pragma unroll
        for (int kb = 0; kb < 2; ++kb)
            #pragma unroll
            for (int r = 0; r < 16; r += 4) {
                if (kb == 0 && r == 0) continue;
                mt0 = fmaxf(mt0, sc[kb][r + 0]);
                mt1 = fmaxf(mt1, sc[kb][r + 1]);
                mt2 = fmaxf(mt2, sc[kb][r + 2]);
                mt3 = fmaxf(mt3, sc[kb][r + 3]);
            }
        const float mt = fmaxf(fmaxf(mt0, mt1), fmaxf(mt2, mt3));
        const float m0 = fmaxf(mt, __shfl_xor(mt, 32, 64));
        const bool need = (m0 > m + THR_LOG2);
        const float mn = need ? fmaxf(m, m0) : m;
        if (__any(need)) {
            const float alpha = exp2f(m - mn);
            m = mn;
            l *= alpha;
            #pragma unroll
            for (int db = 0; db < 4; ++db) acc[db] *= alpha;
        }
        float lsp0 = 0.f, lsp1 = 0.f, lsp2 = 0.f, lsp3 = 0.f;
        #pragma unroll
        for (int kb = 0; kb < 2; ++kb)
            #pragma unroll
            for (int r = 0; r < 16; r += 4) {
                float p0 = exp2f(sc[kb][r + 0] - m);
                float p1 = exp2f(sc[kb][r + 1] - m);
                float p2 = exp2f(sc[kb][r + 2] - m);
                float p3 = exp2f(sc[kb][r + 3] - m);
                sc[kb][r + 0] = p0; sc[kb][r + 1] = p1;
                sc[kb][r + 2] = p2; sc[kb][r + 3] = p3;
                lsp0 += p0; lsp1 += p1; lsp2 += p2; lsp3 += p3;
            }
        l += (lsp0 + lsp1) + (lsp2 + lsp3);

        // ---- P -> B-frag via v_cvt_pk_bf16_f32 + permlane32_swap (T12) ----
        // pa[ks] holds keys 16*ks + 8*hi + {0..7} of row q
        s16x8 pa[4];
        #pragma unroll
        for (int ks = 0; ks < 4; ++ks) {
            const int kb = ks >> 1;
            const int j  = (2 * ks) & 3, j2 = (2 * ks + 1) & 3;
            unsigned a0 = pk2(sc[kb][4 * j + 0],  sc[kb][4 * j + 1]);
            unsigned a1 = pk2(sc[kb][4 * j + 2],  sc[kb][4 * j + 3]);
            unsigned b0 = pk2(sc[kb][4 * j2 + 0], sc[kb][4 * j2 + 1]);
            unsigned b1 = pk2(sc[kb][4 * j2 + 2], sc[kb][4 * j2 + 3]);
#if __has_builtin(__builtin_amdgcn_permlane32_swap)
            auto r0 = __builtin_amdgcn_permlane32_swap(a0, b0, false, false);
            auto r1 = __builtin_amdgcn_permlane32_swap(a1, b1, false, false);
            union { unsigned u[4]; s16x8 v; } P;
            P.u[0] = r0[0]; P.u[1] = r1[0]; P.u[2] = r0[1]; P.u[3] = r1[1];
#else
            const unsigned s0 = __shfl_xor(hi ? a0 : b0, 32, 64);
            const unsigned s1 = __shfl_xor(hi ? a1 : b1, 32, 64);
            union { unsigned u[4]; s16x8 v; } P;
            P.u[0] = hi ? s0 : a0; P.u[1] = hi ? s1 : a1;
            P.u[2] = hi ? b0 : s0; P.u[3] = hi ? b1 : s1;
#endif
            pa[ks] = P.v;
        }

        // ---- PV (swapped): acc[db] += V^T(32d x 16k) * P^T(16k x 32q) ----
        __builtin_amdgcn_s_setprio(1);
        #pragma unroll
        for (int db = 0; db < 4; ++db) {
            const int dim = db * 32 + l32;
            #pragma unroll
            for (int ks = 0; ks < 4; ++ks) {
                const int elem = dim * BK + ((((ks << 1) | hi) ^ (dim & 7)) << 3);
                s16x8 vf = *(const s16x8*)&Vt[bc][elem];
                acc[db] = MFMA32(vf, pa[ks], acc[db]);
            }
        }
        __builtin_amdgcn_s_setprio(0);

        bc = bc + 1 >= 3 ? 0 : bc + 1;
    }

    // ---- epilogue: combine halves' l, normalize, store O fp32 ----
    const float lf = l + __shfl_xor(l, 32, 64);
    const float invl = 1.0f / lf;
    float* op = O + (size_t)q * RSTRIDE + bh * HD;
    #pragma unroll
    for (int db = 0; db < 4; ++db)
        #pragma unroll
        for (int j = 0; j < 4; ++j) {
            f32x4 o;
            #pragma unroll
            for (int r = 0; r < 4; ++r) o[r] = acc[db][4 * j + r] * invl;
            *(f32x4*)(op + db * 32 + j * 8 + hi * 4) = o;
        }
}

// ---------------------------------------------------------------------------
// Legacy fallback (R1 kernel) if ws_size is insufficient.
__global__ __launch_bounds__(256) void fa_fwd_legacy(const float* __restrict__ Q,
                                                     const float* __restrict__ K,
                                                     const float* __restrict__ V,
                                                     float* __restrict__ O) {
    const int qt   = blockIdx.x;
    const int bh   = blockIdx.y;
    const int tid  = threadIdx.x;
    const int w    = tid >> 6;
    const int lane = tid & 63;
    const int l16  = lane & 15;
    const int lg   = lane >> 4;

    __shared__ short Kt[BK * HD];
    __shared__ short Vt[HD * BK];
    __shared__ short Pl[4][16 * 72];

    const int headoff = bh * HD;
    s16x8 qf[4];
    {
        const int qrow = qt * 64 + w * 16 + l16;
        const float* qp = Q + (size_t)qrow * RSTRIDE + headoff + lg * 8;
        #pragma unroll
        for (int ks = 0; ks < 4; ++ks) {
            f32x4 a = *(const f32x4*)(qp + ks * 32);
            f32x4 b = *(const f32x4*)(qp + ks * 32 + 4);
            s16x8 f;
            #pragma unroll
            for (int j = 0; j < 4; ++j) {
                f[j]     = f2bf(a[j] * SCALE_LOG2E);
                f[4 + j] = f2bf(b[j] * SCALE_LOG2E);
            }
            qf[ks] = f;
        }
    }
    f32x4 acc[8];
    #pragma unroll
    for (int i = 0; i < 8; ++i)
        #pragma unroll
        for (int j = 0; j < 4; ++j) acc[i][j] = 0.0f;
    float mrow[4], lrow[4];
    #pragma unroll
    for (int r = 0; r < 4; ++r) { mrow[r] = -INFINITY; lrow[r] = 0.0f; }
    const int skey = tid >> 2;
    const int sdc  = tid & 3;
    const int va   = tid >> 3;
    const int vdc  = tid & 7;

    for (int kt = 0; kt < NKT; ++kt) {
        __syncthreads();
        {
            const float* kp = K + (size_t)(kt * BK + skey) * RSTRIDE + headoff;
            #pragma unroll
            for (int c = 0; c < 4; ++c) {
                const int d0 = c * 32 + sdc * 8;
                f32x4 a = *(const f32x4*)(kp + d0);
                f32x4 b = *(const f32x4*)(kp + d0 + 4);
                s16x8 f;
                #pragma unroll
                for (int j = 0; j < 4; ++j) { f[j] = f2bf(a[j]); f[4 + j] = f2bf(b[j]); }
                const int elem = (skey * HD + d0) ^ ((skey & 7) << 3);
                *(s16x8*)&Kt[elem] = f;
            }
        }
        {
            const float* vp0 = V + (size_t)(kt * BK + va * 2) * RSTRIDE + headoff;
            const float* vp1 = vp0 + RSTRIDE;
            #pragma unroll
            for (int c = 0; c < 4; ++c) {
                const int d0 = c * 32 + vdc * 4;
                f32x4 a0 = *(const f32x4*)(vp0 + d0);
                f32x4 a1 = *(const f32x4*)(vp1 + d0);
                #pragma unroll
                for (int j = 0; j < 4; ++j) {
                    const int dim = d0 + j;
                    const int s = (dim ^ (dim >> 3)) & 7;
                    const int elem = (dim * BK + va * 2) ^ (s << 3);
                    union { short u[2]; int i; } pr;
                    pr.u[0] = f2bf(a0[j]);
                    pr.u[1] = f2bf(a1[j]);
                    *(int*)&Vt[elem] = pr.i;
                }
            }
        }
        __syncthreads();
        f32x4 sc[4];
        #pragma unroll
        for (int t = 0; t < 4; ++t) {
            #pragma unroll
            for (int j = 0; j < 4; ++j) sc[t][j] = 0.0f;
            const int key = t * 16 + l16;
            #pragma unroll
            for (int ks = 0; ks < 4; ++ks) {
                const int elem = (key * HD + ks * 32 + lg * 8) ^ ((key & 7) << 3);
                s16x8 kf = *(const s16x8*)&Kt[elem];
                sc[t] = __builtin_amdgcn_mfma_f32_16x16x32_bf16(qf[ks], kf, sc[t], 0, 0, 0);
            }
        }
        float alpha[4];
        #pragma unroll
        for (int r = 0; r < 4; ++r) {
            float m0 = fmaxf(fmaxf(sc[0][r], sc[1][r]), fmaxf(sc[2][r], sc[3][r]));
            #pragma unroll
            for (int d = 1; d < 16; d <<= 1) m0 = fmaxf(m0, __shfl_xor(m0, d, 64));
            const float mnew = fmaxf(mrow[r], m0);
            alpha[r] = exp2f(mrow[r] - mnew);
            mrow[r] = mnew;
        }
        float rsum[4] = {0.f, 0.f, 0.f, 0.f};
        #pragma unroll
        for (int t = 0; t < 4; ++t)
            #pragma unroll
            for (int r = 0; r < 4; ++r) {
                const float p = exp2f(sc[t][r] - mrow[r]);
                sc[t][r] = p;
                rsum[r] += p;
            }
        #pragma unroll
        for (int r = 0; r < 4; ++r) {
            #pragma unroll
            for (int d = 1; d < 16; d <<= 1) rsum[r] += __shfl_xor(rsum[r], d, 64);
            lrow[r] = lrow[r] * alpha[r] + rsum[r];
        }
        #pragma unroll
        for (int ct = 0; ct < 8; ++ct)
            #pragma unroll
            for (int r = 0; r < 4; ++r) acc[ct][r] *= alpha[r];
        #pragma unroll
        for (int t = 0; t < 4; ++t)
            #pragma unroll
            for (int r = 0; r < 4; ++r)
                Pl[w][(lg * 4 + r) * 72 + t * 16 + l16] = f2bf(sc[t][r]);
        s16x8 pf[2];
        #pragma unroll
        for (int ks = 0; ks < 2; ++ks)
            pf[ks] = *(const s16x8*)&Pl[w][l16 * 72 + ks * 32 + lg * 8];
        #pragma unroll
        for (int ct = 0; ct < 8; ++ct) {
            const int dim = ct * 16 + l16;
            const int s = (dim ^ (dim >> 3)) & 7;
            #pragma unroll
            for (int ks = 0; ks < 2; ++ks) {
                const int elem = (dim * BK + ks * 32 + lg * 8) ^ (s << 3);
                s16x8 vf = *(const s16x8*)&Vt[elem];
                acc[ct] = __builtin_amdgcn_mfma_f32_16x16x32_bf16(pf[ks], vf, acc[ct], 0, 0, 0);
            }
        }
    }
    float inv_l[4];
    #pragma unroll
    for (int r = 0; r < 4; ++r) inv_l[r] = 1.0f / lrow[r];
    const int orow0 = qt * 64 + w * 16;
    #pragma unroll
    for (int ct = 0; ct < 8; ++ct) {
        const int col = ct * 16 + l16;
        #pragma unroll
        for (int r = 0; r < 4; ++r) {
            const int row = orow0 + lg * 4 + r;
            O[(size_t)row * RSTRIDE + headoff + col] = acc[ct][r] * inv_l[r];
        }
    }
}

extern "C" void kernel_launch(void* const* d_in, const int* in_sizes, int n_in,
                              void* d_out, int out_size, void* d_ws, size_t ws_size,
                              hipStream_t stream) {
    const float* Q = (const float*)d_in[0];
    const float* K = (const float*)d_in[1];
    const float* V = (const float*)d_in[2];
    float* O = (float*)d_out;

    const size_t need = (size_t)3 * NBH * HELEMS * sizeof(short);  // 50.3 MB
    if (ws_size >= need) {
        short* wq = (short*)d_ws;
        short* wk = wq + (size_t)NBH * HELEMS;
        short* wv = wk + (size_t)NBH * HELEMS;
        prep_qk<<<4096, 256, 0, stream>>>(Q, K, wq, wk);
        prep_v<<<dim3(NKT, NBH), 256, 0, stream>>>(V, wv);
        fa_fwd3<<<(SQ / BQ) * NBH, 512, 0, stream>>>(wq, wk, wv, O);
    } else {
        fa_fwd_legacy<<<dim3(SQ / 64, NBH), 256, 0, stream>>>(Q, K, V, O);
    }
}

// Round 7
// 119.217 us; speedup vs baseline: 1.5141x; 1.1171x over previous
//
#include <hip/hip_runtime.h>
#include <hip/hip_bf16.h>
#include <math.h>

// DotProductAttention: S=2048, B=2, NH=16, HD=128, fp32 in/out, mask=all-ones.
// R7: R4 skeleton (STAGE-first, one __syncthreads per tile — best measured)
//   + XCD swizzle (R5's proven win) + cross-iteration software pipeline:
//   iteration t computes softmax(t)/pack(t) [VALU] overlapped with
//   QK^T(t+1) and PV(t) [MFMA pipe], triple-buffered LDS (96 KB).

#define SQ 2048
#define NBH 32
#define HD 128
#define RSTRIDE 4096          // B*NH*HD
#define BQ 256                // q-rows per block (8 waves x 32)
#define BK 64                 // kv tile
#define NKT (SQ / BK)
#define HELEMS (SQ * HD)      // per-head elems per tensor
#define SCALE_LOG2E 0.12751879523499918f  // log2(e)/sqrt(128)
#define THR_LOG2 8.0f

typedef __attribute__((ext_vector_type(4)))  float f32x4;
typedef __attribute__((ext_vector_type(16))) float f32x16;
typedef __attribute__((ext_vector_type(4)))  short s16x4;
typedef __attribute__((ext_vector_type(8)))  short s16x8;

#define MFMA32(a, b, c) __builtin_amdgcn_mfma_f32_32x32x16_bf16((a), (b), (c), 0, 0, 0)

__device__ __forceinline__ short f2bf(float f) {
    __hip_bfloat16 h = __float2bfloat16(f);
    return __builtin_bit_cast(short, h);
}
__device__ __forceinline__ unsigned pk2(float lo, float hi) {
    unsigned r;
    asm("v_cvt_pk_bf16_f32 %0, %1, %2" : "=v"(r) : "v"(lo), "v"(hi));
    return r;
}

__device__ __forceinline__ void stage16(const void* g, void* l) {
    __builtin_amdgcn_global_load_lds(
        (const __attribute__((address_space(1))) unsigned int*)g,
        (__attribute__((address_space(3))) unsigned int*)l, 16, 0, 0);
}

// ---------------------------------------------------------------------------
// Pre-pass 1: Q,K fp32 [s][bh][hd] -> bf16 [bh][s][hd] in ws.
// Q scaled by SCALE_LOG2E (plain layout). K: 16B chunks pre-swizzled
// (c ^= s&7) so linear global_load_lds yields the swizzled LDS image.
__global__ __launch_bounds__(256) void prep_qk(const float* __restrict__ Q,
                                               const float* __restrict__ K,
                                               short* __restrict__ wq,
                                               short* __restrict__ wk) {
    const int id = blockIdx.x * 256 + threadIdx.x;   // 1M chunk ids
    const int bh = id >> 15;
    const int s  = (id >> 4) & 2047;
    const int c  = id & 15;
    const size_t outoff = (size_t)bh * HELEMS + (size_t)s * HD + c * 8;
    {   // Q (plain)
        const float* src = Q + (size_t)s * RSTRIDE + bh * HD + c * 8;
        f32x4 a = *(const f32x4*)src;
        f32x4 b = *(const f32x4*)(src + 4);
        s16x8 f;
        #pragma unroll
        for (int j = 0; j < 4; ++j) {
            f[j]     = f2bf(a[j] * SCALE_LOG2E);
            f[4 + j] = f2bf(b[j] * SCALE_LOG2E);
        }
        *(s16x8*)(wq + outoff) = f;
    }
    {   // K (chunk-swizzled)
        const int cl = c ^ (s & 7);
        const float* src = K + (size_t)s * RSTRIDE + bh * HD + cl * 8;
        f32x4 a = *(const f32x4*)src;
        f32x4 b = *(const f32x4*)(src + 4);
        s16x8 f;
        #pragma unroll
        for (int j = 0; j < 4; ++j) { f[j] = f2bf(a[j]); f[4 + j] = f2bf(b[j]); }
        *(s16x8*)(wk + outoff) = f;
    }
}

// ---------------------------------------------------------------------------
// Pre-pass 2: V fp32 [s][bh][hd] -> bf16 transposed [bh][dim][s] in ws,
// 8-key chunks pre-swizzled per 64-key block: ws[bh][dim][kt*64 + c*8 + j] =
//   V[kt*64 + (c^(dim&7))*8 + j][bh][dim].
__global__ __launch_bounds__(256) void prep_v(const float* __restrict__ V,
                                              short* __restrict__ wv) {
    const int kt = blockIdx.x;   // 32
    const int bh = blockIdx.y;   // 32
    const int tid = threadIdx.x;
    __shared__ short L[64 * 132];  // [key_local][dim], pitch 132 (128+4 pad)

    #pragma unroll
    for (int it = 0; it < 8; ++it) {
        const int id = it * 256 + tid;       // 0..2047
        const int row = id >> 5, p = id & 31;
        f32x4 a = *(const f32x4*)(V + (size_t)(kt * BK + row) * RSTRIDE + bh * HD + p * 4);
        s16x4 f;
        #pragma unroll
        for (int j = 0; j < 4; ++j) f[j] = f2bf(a[j]);
        *(s16x4*)&L[row * 132 + p * 4] = f;
    }
    __syncthreads();
    #pragma unroll
    for (int it = 0; it < 4; ++it) {
        const int id = it * 256 + tid;       // 0..1023
        const int dim = id >> 3, c = id & 7;
        const int klb = (c ^ (dim & 7)) * 8;
        s16x8 f;
        #pragma unroll
        for (int j = 0; j < 8; ++j) f[j] = L[(klb + j) * 132 + dim];
        *(s16x8*)(wv + (size_t)bh * HELEMS + (size_t)dim * SQ + kt * BK + c * 8) = f;
    }
}

// ---------------------------------------------------------------------------
// Main flash kernel: 8 waves x 32 q-rows (BQ=256); swapped-operand 32x32x16.
// Grid = 256 linear blocks, XCD-swizzled. Cross-iteration pipeline:
// body(t) = { STAGE(t+2); softmax(t); pack(t); QKT(t+1); PV(t); sync }.
__global__ __launch_bounds__(512) void fa_fwd4(const short* __restrict__ Qb,
                                               const short* __restrict__ Kb,
                                               const short* __restrict__ Vb,
                                               float* __restrict__ O) {
    // XCD-aware decode: dispatch round-robins id%8 across XCDs -> XCD x owns
    // heads 4x..4x+3 (K/V panels: 4 MB = one XCD L2).
    const int id  = blockIdx.x;
    const int xcd = id & 7;
    const int s8  = id >> 3;          // 0..31
    const int bh  = xcd * 4 + (s8 >> 3);
    const int qt  = s8 & 7;

    const int tid  = threadIdx.x;
    const int w    = tid >> 6;     // wave 0..7
    const int lane = tid & 63;
    const int l32  = lane & 31;
    const int hi   = lane >> 5;

    __shared__ short Kt[3][BK * HD];   // [key][dim] swizzled image, 3x16KB
    __shared__ short Vt[3][HD * BK];   // [dim][key] swizzled image, 3x16KB

    const size_t hb = (size_t)bh * HELEMS;
    const int q = qt * BQ + w * 32 + l32;   // this lane's q-row

    // Q fragments: qf[kd][i] = Q[q][16*kd + 8*hi + i], scale pre-folded
    s16x8 qf[8];
    {
        const short* qp = Qb + hb + (size_t)q * HD + hi * 8;
        #pragma unroll
        for (int kd = 0; kd < 8; ++kd) qf[kd] = *(const s16x8*)(qp + kd * 16);
    }

    // acc[db][reg] = O[q][32*db + (reg&3) + 8*(reg>>2) + 4*hi]  (O^T orient.)
    f32x16 acc[4];
    #pragma unroll
    for (int db = 0; db < 4; ++db)
        #pragma unroll
        for (int i = 0; i < 16; ++i) acc[db][i] = 0.0f;
    float m = -INFINITY, l = 0.0f;

    // staging roles: waves 0-3 stage K, waves 4-7 stage V (4x16B each).
    auto STAGE = [&](int kt, int buf) {
        if (w < 4) {
            const short* kg = Kb + hb + (size_t)kt * (BK * HD) + w * 2048 + lane * 8;
            short* ld = &Kt[buf][w * 2048 + lane * 8];
            #pragma unroll
            for (int j = 0; j < 4; ++j)
                stage16(kg + j * 512, ld + j * 512);
        } else {
            const int w4 = w - 4;
            #pragma unroll
            for (int j = 0; j < 4; ++j) {
                const int dim = w4 * 32 + j * 8 + (lane >> 3);
                const short* vg = Vb + hb + (size_t)dim * SQ + kt * BK + (lane & 7) * 8;
                stage16(vg, &Vt[buf][(w4 * 32 + j * 8) * BK + lane * 8]);
            }
        }
    };

    // QK^T (swapped): sc[kb] = S^T tile; lane holds 16 keys of row q per kb.
    // key = 32*kb + (reg&3) + 8*(reg>>2) + 4*hi
    auto QKT = [&](int bufi, f32x16* sc) {
        const short* Kb_ = Kt[bufi];
        __builtin_amdgcn_s_setprio(1);
        #pragma unroll
        for (int kb = 0; kb < 2; ++kb) {
            #pragma unroll
            for (int i = 0; i < 16; ++i) sc[kb][i] = 0.0f;
            const int key = kb * 32 + l32;
            #pragma unroll
            for (int kd = 0; kd < 8; ++kd) {
                const int elem = key * HD + (((kd << 1) | hi) ^ (key & 7)) * 8;
                s16x8 kf = *(const s16x8*)&Kb_[elem];
                sc[kb] = MFMA32(kf, qf[kd], sc[kb]);
            }
        }
        __builtin_amdgcn_s_setprio(0);
    };

    // softmax(t) on sc + pack into pa (B-frag): updates m, l, acc.
    auto SOFTPACK = [&](f32x16* sc, s16x8* pa) {
        float mt0 = sc[0][0], mt1 = sc[0][1], mt2 = sc[0][2], mt3 = sc[0][3];
        #pragma unroll
        for (int kb = 0; kb < 2; ++kb)
            #pragma unroll
            for (int r = 0; r < 16; r += 4) {
                if (kb == 0 && r == 0) continue;
                mt0 = fmaxf(mt0, sc[kb][r + 0]);
                mt1 = fmaxf(mt1, sc[kb][r + 1]);
                mt2 = fmaxf(mt2, sc[kb][r + 2]);
                mt3 = fmaxf(mt3, sc[kb][r + 3]);
            }
        const float mt = fmaxf(fmaxf(mt0, mt1), fmaxf(mt2, mt3));
        const float m0 = fmaxf(mt, __shfl_xor(mt, 32, 64));
        const bool need = (m0 > m + THR_LOG2);
        const float mn = need ? fmaxf(m, m0) : m;
        if (__any(need)) {
            const float alpha = exp2f(m - mn);
            m = mn;
            l *= alpha;
            #pragma unroll
            for (int db = 0; db < 4; ++db) acc[db] *= alpha;
        }
        float lsp0 = 0.f, lsp1 = 0.f, lsp2 = 0.f, lsp3 = 0.f;
        #pragma unroll
        for (int kb = 0; kb < 2; ++kb)
            #pragma unroll
            for (int r = 0; r < 16; r += 4) {
                float p0 = exp2f(sc[kb][r + 0] - m);
                float p1 = exp2f(sc[kb][r + 1] - m);
                float p2 = exp2f(sc[kb][r + 2] - m);
                float p3 = exp2f(sc[kb][r + 3] - m);
                sc[kb][r + 0] = p0; sc[kb][r + 1] = p1;
                sc[kb][r + 2] = p2; sc[kb][r + 3] = p3;
                lsp0 += p0; lsp1 += p1; lsp2 += p2; lsp3 += p3;
            }
        l += (lsp0 + lsp1) + (lsp2 + lsp3);

        // pa[ks] holds keys 16*ks + 8*hi + {0..7} of row q
        #pragma unroll
        for (int ks = 0; ks < 4; ++ks) {
            const int kb = ks >> 1;
            const int j  = (2 * ks) & 3, j2 = (2 * ks + 1) & 3;
            unsigned a0 = pk2(sc[kb][4 * j + 0],  sc[kb][4 * j + 1]);
            unsigned a1 = pk2(sc[kb][4 * j + 2],  sc[kb][4 * j + 3]);
            unsigned b0 = pk2(sc[kb][4 * j2 + 0], sc[kb][4 * j2 + 1]);
            unsigned b1 = pk2(sc[kb][4 * j2 + 2], sc[kb][4 * j2 + 3]);
#if __has_builtin(__builtin_amdgcn_permlane32_swap)
            auto r0 = __builtin_amdgcn_permlane32_swap(a0, b0, false, false);
            auto r1 = __builtin_amdgcn_permlane32_swap(a1, b1, false, false);
            union { unsigned u[4]; s16x8 v; } P;
            P.u[0] = r0[0]; P.u[1] = r1[0]; P.u[2] = r0[1]; P.u[3] = r1[1];
#else
            const unsigned s0 = __shfl_xor(hi ? a0 : b0, 32, 64);
            const unsigned s1 = __shfl_xor(hi ? a1 : b1, 32, 64);
            union { unsigned u[4]; s16x8 v; } P;
            P.u[0] = hi ? s0 : a0; P.u[1] = hi ? s1 : a1;
            P.u[2] = hi ? b0 : s0; P.u[3] = hi ? b1 : s1;
#endif
            pa[ks] = P.v;
        }
    };

    // PV (swapped): acc[db] += V^T(32d x 16k) * P^T(16k x 32q)
    auto PV = [&](int bufi, s16x8* pa) {
        const short* Vb_ = Vt[bufi];
        __builtin_amdgcn_s_setprio(1);
        #pragma unroll
        for (int db = 0; db < 4; ++db) {
            const int dim = db * 32 + l32;
            #pragma unroll
            for (int ks = 0; ks < 4; ++ks) {
                const int elem = dim * BK + ((((ks << 1) | hi) ^ (dim & 7)) << 3);
                s16x8 vf = *(const s16x8*)&Vb_[elem];
                acc[db] = MFMA32(vf, pa[ks], acc[db]);
            }
        }
        __builtin_amdgcn_s_setprio(0);
    };

    // ---- pipeline prologue ----
    f32x16 scA[2], scB[2];
    s16x8 paA[4], paB[4];

    STAGE(0, 0);
    __syncthreads();        // K0/V0 ready
    QKT(0, scA);            // sc(0)
    STAGE(1, 1);            // tile 1 in flight

    // ---- main loop: 16 iterations x 2 tiles, register ping-pong scA/scB ----
    #pragma unroll 1
    for (int i = 0; i < NKT / 2; ++i) {
        const int t0 = 2 * i;
        // ---- even tile t0: uses scA, computes scB = sc(t0+1) ----
        __syncthreads();    // drains STAGE(t0+1); buffer (t0+2)%3 free
        if (t0 + 2 < NKT) STAGE(t0 + 2, (t0 + 2) % 3);
        SOFTPACK(scA, paA);
        if (t0 + 1 < NKT) QKT((t0 + 1) % 3, scB);
        PV(t0 % 3, paA);
        // ---- odd tile t1 = t0+1: uses scB, computes scA = sc(t0+2) ----
        __syncthreads();    // drains STAGE(t0+2); buffer (t0+3)%3 free
        if (t0 + 3 < NKT) STAGE(t0 + 3, (t0 + 3) % 3);
        SOFTPACK(scB, paB);
        if (t0 + 2 < NKT) QKT((t0 + 2) % 3, scA);
        PV((t0 + 1) % 3, paB);
    }

    // ---- epilogue: combine halves' l, normalize, store O fp32 ----
    const float lf = l + __shfl_xor(l, 32, 64);
    const float invl = 1.0f / lf;
    float* op = O + (size_t)q * RSTRIDE + bh * HD;
    #pragma unroll
    for (int db = 0; db < 4; ++db)
        #pragma unroll
        for (int j = 0; j < 4; ++j) {
            f32x4 o;
            #pragma unroll
            for (int r = 0; r < 4; ++r) o[r] = acc[db][4 * j + r] * invl;
            *(f32x4*)(op + db * 32 + j * 8 + hi * 4) = o;
        }
}

// ---------------------------------------------------------------------------
// Legacy fallback (R1 kernel) if ws_size is insufficient.
__global__ __launch_bounds__(256) void fa_fwd_legacy(const float* __restrict__ Q,
                                                     const float* __restrict__ K,
                                                     const float* __restrict__ V,
                                                     float* __restrict__ O) {
    const int qt   = blockIdx.x;
    const int bh   = blockIdx.y;
    const int tid  = threadIdx.x;
    const int w    = tid >> 6;
    const int lane = tid & 63;
    const int l16  = lane & 15;
    const int lg   = lane >> 4;

    __shared__ short Kt[BK * HD];
    __shared__ short Vt[HD * BK];
    __shared__ short Pl[4][16 * 72];

    const int headoff = bh * HD;
    s16x8 qf[4];
    {
        const int qrow = qt * 64 + w * 16 + l16;
        const float* qp = Q + (size_t)qrow * RSTRIDE + headoff + lg * 8;
        #pragma unroll
        for (int ks = 0; ks < 4; ++ks) {
            f32x4 a = *(const f32x4*)(qp + ks * 32);
            f32x4 b = *(const f32x4*)(qp + ks * 32 + 4);
            s16x8 f;
            #pragma unroll
            for (int j = 0; j < 4; ++j) {
                f[j]     = f2bf(a[j] * SCALE_LOG2E);
                f[4 + j] = f2bf(b[j] * SCALE_LOG2E);
            }
            qf[ks] = f;
        }
    }
    f32x4 acc[8];
    #pragma unroll
    for (int i = 0; i < 8; ++i)
        #pragma unroll
        for (int j = 0; j < 4; ++j) acc[i][j] = 0.0f;
    float mrow[4], lrow[4];
    #pragma unroll
    for (int r = 0; r < 4; ++r) { mrow[r] = -INFINITY; lrow[r] = 0.0f; }
    const int skey = tid >> 2;
    const int sdc  = tid & 3;
    const int va   = tid >> 3;
    const int vdc  = tid & 7;

    for (int kt = 0; kt < NKT; ++kt) {
        __syncthreads();
        {
            const float* kp = K + (size_t)(kt * BK + skey) * RSTRIDE + headoff;
            #pragma unroll
            for (int c = 0; c < 4; ++c) {
                const int d0 = c * 32 + sdc * 8;
                f32x4 a = *(const f32x4*)(kp + d0);
                f32x4 b = *(const f32x4*)(kp + d0 + 4);
                s16x8 f;
                #pragma unroll
                for (int j = 0; j < 4; ++j) { f[j] = f2bf(a[j]); f[4 + j] = f2bf(b[j]); }
                const int elem = (skey * HD + d0) ^ ((skey & 7) << 3);
                *(s16x8*)&Kt[elem] = f;
            }
        }
        {
            const float* vp0 = V + (size_t)(kt * BK + va * 2) * RSTRIDE + headoff;
            const float* vp1 = vp0 + RSTRIDE;
            #pragma unroll
            for (int c = 0; c < 4; ++c) {
                const int d0 = c * 32 + vdc * 4;
                f32x4 a0 = *(const f32x4*)(vp0 + d0);
                f32x4 a1 = *(const f32x4*)(vp1 + d0);
                #pragma unroll
                for (int j = 0; j < 4; ++j) {
                    const int dim = d0 + j;
                    const int s = (dim ^ (dim >> 3)) & 7;
                    const int elem = (dim * BK + va * 2) ^ (s << 3);
                    union { short u[2]; int i; } pr;
                    pr.u[0] = f2bf(a0[j]);
                    pr.u[1] = f2bf(a1[j]);
                    *(int*)&Vt[elem] = pr.i;
                }
            }
        }
        __syncthreads();
        f32x4 sc[4];
        #pragma unroll
        for (int t = 0; t < 4; ++t) {
            #pragma unroll
            for (int j = 0; j < 4; ++j) sc[t][j] = 0.0f;
            const int key = t * 16 + l16;
            #pragma unroll
            for (int ks = 0; ks < 4; ++ks) {
                const int elem = (key * HD + ks * 32 + lg * 8) ^ ((key & 7) << 3);
                s16x8 kf = *(const s16x8*)&Kt[elem];
                sc[t] = __builtin_amdgcn_mfma_f32_16x16x32_bf16(qf[ks], kf, sc[t], 0, 0, 0);
            }
        }
        float alpha[4];
        #pragma unroll
        for (int r = 0; r < 4; ++r) {
            float m0 = fmaxf(fmaxf(sc[0][r], sc[1][r]), fmaxf(sc[2][r], sc[3][r]));
            #pragma unroll
            for (int d = 1; d < 16; d <<= 1) m0 = fmaxf(m0, __shfl_xor(m0, d, 64));
            const float mnew = fmaxf(mrow[r], m0);
            alpha[r] = exp2f(mrow[r] - mnew);
            mrow[r] = mnew;
        }
        float rsum[4] = {0.f, 0.f, 0.f, 0.f};
        #pragma unroll
        for (int t = 0; t < 4; ++t)
            #pragma unroll
            for (int r = 0; r < 4; ++r) {
                const float p = exp2f(sc[t][r] - mrow[r]);
                sc[t][r] = p;
                rsum[r] += p;
            }
        #pragma unroll
        for (int r = 0; r < 4; ++r) {
            #pragma unroll
            for (int d = 1; d < 16; d <<= 1) rsum[r] += __shfl_xor(rsum[r], d, 64);
            lrow[r] = lrow[r] * alpha[r] + rsum[r];
        }
        #pragma unroll
        for (int ct = 0; ct < 8; ++ct)
            #pragma unroll
            for (int r = 0; r < 4; ++r) acc[ct][r] *= alpha[r];
        #pragma unroll
        for (int t = 0; t < 4; ++t)
            #pragma unroll
            for (int r = 0; r < 4; ++r)
                Pl[w][(lg * 4 + r) * 72 + t * 16 + l16] = f2bf(sc[t][r]);
        s16x8 pf[2];
        #pragma unroll
        for (int ks = 0; ks < 2; ++ks)
            pf[ks] = *(const s16x8*)&Pl[w][l16 * 72 + ks * 32 + lg * 8];
        #pragma unroll
        for (int ct = 0; ct < 8; ++ct) {
            const int dim = ct * 16 + l16;
            const int s = (dim ^ (dim >> 3)) & 7;
            #pragma unroll
            for (int ks = 0; ks < 2; ++ks) {
                const int elem = (dim * BK + ks * 32 + lg * 8) ^ (s << 3);
                s16x8 vf = *(const s16x8*)&Vt[elem];
                acc[ct] = __builtin_amdgcn_mfma_f32_16x16x32_bf16(pf[ks], vf, acc[ct], 0, 0, 0);
            }
        }
    }
    float inv_l[4];
    #pragma unroll
    for (int r = 0; r < 4; ++r) inv_l[r] = 1.0f / lrow[r];
    const int orow0 = qt * 64 + w * 16;
    #pragma unroll
    for (int ct = 0; ct < 8; ++ct) {
        const int col = ct * 16 + l16;
        #pragma unroll
        for (int r = 0; r < 4; ++r) {
            const int row = orow0 + lg * 4 + r;
            O[(size_t)row * RSTRIDE + headoff + col] = acc[ct][r] * inv_l[r];
        }
    }
}

extern "C" void kernel_launch(void* const* d_in, const int* in_sizes, int n_in,
                              void* d_out, int out_size, void* d_ws, size_t ws_size,
                              hipStream_t stream) {
    const float* Q = (const float*)d_in[0];
    const float* K = (const float*)d_in[1];
    const float* V = (const float*)d_in[2];
    float* O = (float*)d_out;

    const size_t need = (size_t)3 * NBH * HELEMS * sizeof(short);  // 50.3 MB
    if (ws_size >= need) {
        short* wq = (short*)d_ws;
        short* wk = wq + (size_t)NBH * HELEMS;
        short* wv = wk + (size_t)NBH * HELEMS;
        prep_qk<<<4096, 256, 0, stream>>>(Q, K, wq, wk);
        prep_v<<<dim3(NKT, NBH), 256, 0, stream>>>(V, wv);
        fa_fwd4<<<(SQ / BQ) * NBH, 512, 0, stream>>>(wq, wk, wv, O);
    } else {
        fa_fwd_legacy<<<dim3(SQ / 64, NBH), 256, 0, stream>>>(Q, K, V, O);
    }
}